// Round 7
// baseline (1066.160 us; speedup 1.0000x reference)
//
#include <hip/hip_runtime.h>
#include <hip/hip_bf16.h>
#include <cstdint>

#define M_DIM 8192
#define K_DIM 4096
#define N_DIM 11008
#define NGROUPS 32

typedef __attribute__((ext_vector_type(4))) float f32x4;
typedef __attribute__((ext_vector_type(8))) __bf16 bf16x8;

__device__ __forceinline__ unsigned int f2bf(float f) {
  unsigned int u = __builtin_bit_cast(unsigned int, f);
  return (u + 0x7FFFu + ((u >> 16) & 1u)) >> 16;   // RNE f32->bf16
}
__device__ __forceinline__ unsigned int pk2(float lo, float hi) {
  return f2bf(lo) | (f2bf(hi) << 16);
}

// ---------------- prepass: A fp32 -> bf16 ----------------
__global__ __launch_bounds__(256) void cvtA_kernel(const float* __restrict__ in,
                                                   unsigned short* __restrict__ outA) {
  size_t g = (size_t)blockIdx.x * 256 + threadIdx.x;
  size_t base = g * 8;
  const float4* p = (const float4*)(in + base);
  float4 a = p[0], b = p[1];
  uint4 v;
  v.x = pk2(a.x, a.y); v.y = pk2(a.z, a.w);
  v.z = pk2(b.x, b.y); v.w = pk2(b.z, b.w);
  *(uint4*)(outA + base) = v;
}

// ---------------- prepass: W int codes * scale -> bf16 ----------------
__global__ __launch_bounds__(256) void dequantW_kernel(const int* __restrict__ w,
                                                       const float* __restrict__ sc,
                                                       unsigned short* __restrict__ outB) {
  size_t g = (size_t)blockIdx.x * 256 + threadIdx.x;
  size_t base = g * 8;
  unsigned n = (unsigned)(base >> 12);
  unsigned k = (unsigned)base & 4095u;
  float s = sc[n * NGROUPS + (k >> 7)];
  const int4* p = (const int4*)(w + base);
  int4 c0 = p[0], c1 = p[1];
  uint4 v;
  v.x = pk2((float)c0.x * s, (float)c0.y * s);
  v.y = pk2((float)c0.z * s, (float)c0.w * s);
  v.z = pk2((float)c1.x * s, (float)c1.y * s);
  v.w = pk2((float)c1.z * s, (float)c1.w * s);
  *(uint4*)(outB + base) = v;
}

__device__ __forceinline__ void gload16(const void* g, void* l) {
  __builtin_amdgcn_global_load_lds((const __attribute__((address_space(1))) void*)g,
                                   (__attribute__((address_space(3))) void*)l,
                                   16, 0, 0);
}

// === 128x256, BK=32, 3-deep rotation, 2 blocks/CU (cross-block TLP) ===
#define BM 128
#define BN 256
#define BK 32
#define NKT (K_DIM / BK)          /* 128 */
#define TILES_M (M_DIM / BM)      /* 64 */
#define TILES_N (N_DIM / BN)      /* 43 */
#define NB (TILES_M * TILES_N)    /* 2752, %8==0 */
#define TSZA (BM * BK)            /* 4096 elem = 8 KiB */
#define TSZB (BN * BK)            /* 8192 elem = 16 KiB */

#define VMCNT_(n) asm volatile("s_waitcnt vmcnt(" #n ")" ::: "memory")
#define VMCNT(n) VMCNT_(n)
#define BAR()                                   \
  do {                                          \
    asm volatile("" ::: "memory");              \
    __builtin_amdgcn_s_barrier();               \
    asm volatile("" ::: "memory");              \
  } while (0)

__global__ __launch_bounds__(512, 4) void gemm8_kernel(
    const unsigned short* __restrict__ A,   // bf16 [M][K]
    const unsigned short* __restrict__ B,   // bf16 [N][K]
    const float* __restrict__ bias,
    float* __restrict__ out) {
  __shared__ unsigned short sA[3][TSZA];   // 24 KiB
  __shared__ unsigned short sB[3][TSZB];   // 48 KiB  (72 total -> 2 blocks/CU)

  const int t = threadIdx.x;
  const int bid = blockIdx.x;
  const int wg = (bid & 7) * (NB / 8) + (bid >> 3);   // bijective XCD swizzle
  const int m0 = (wg / TILES_N) * BM;
  const int n0 = (wg % TILES_N) * BN;

  const int w = t >> 6;
  const int lane = t & 63;
  const int wm = w >> 2;   // 0..1  (64 rows each)
  const int wn = w & 3;    // 0..3  (64 cols each)

  // ---- staging: per tile 1 A-instr + 2 B-instr per thread (24 KiB total)
  // thread t covers row t>>2, phys granule t&3; source pre-swizzled (rule #21):
  // src granule = (t&3) ^ ((row>>1)&3); LDS dest linear (wave-uniform base + 16*lane)
  const int srow = t >> 2;                 // 0..127
  const int sgr = (t & 3) ^ ((srow >> 1) & 3);
  const unsigned aoff = (unsigned)(m0 + srow) * K_DIM + (unsigned)sgr * 8;
  const unsigned boff0 = (unsigned)(n0 + srow) * K_DIM + (unsigned)sgr * 8;
  const unsigned boff1 = (unsigned)(n0 + 128 + srow) * K_DIM + (unsigned)sgr * 8;
  const int ldsA = (w * 16) * BK;          // wave-uniform elem offset
  const int ldsB0 = (w * 16) * BK;
  const int ldsB1 = (128 + w * 16) * BK;

  f32x4 acc[4][4];
#pragma unroll
  for (int i = 0; i < 4; ++i)
#pragma unroll
    for (int j = 0; j < 4; ++j) {
      f32x4 z = {0.f, 0.f, 0.f, 0.f};
      acc[i][j] = z;
    }

  const int arow_base = wm * 64 + (lane & 15);
  const int brow_base = wn * 64 + (lane & 15);
  const int kgr = lane >> 4;               // 0..3 logical granule

#define STAGE(buf, kt)                                                        \
  do {                                                                        \
    gload16(A + aoff + (unsigned)(kt) * BK, &sA[buf][ldsA]);                  \
    gload16(B + boff0 + (unsigned)(kt) * BK, &sB[buf][ldsB0]);                \
    gload16(B + boff1 + (unsigned)(kt) * BK, &sB[buf][ldsB1]);                \
  } while (0)

#define TILE_BODY(CB)                                                         \
  bf16x8 af[4], bf[4];                                                        \
  _Pragma("unroll") for (int i = 0; i < 4; ++i) {                             \
    const int row = arow_base + i * 16;                                       \
    const int pg = kgr ^ ((row >> 1) & 3);                                    \
    af[i] = *(const bf16x8*)&sA[CB][row * BK + pg * 8];                       \
  }                                                                           \
  _Pragma("unroll") for (int j = 0; j < 4; ++j) {                             \
    const int row = brow_base + j * 16;                                       \
    const int pg = kgr ^ ((row >> 1) & 3);                                    \
    bf[j] = *(const bf16x8*)&sB[CB][row * BK + pg * 8];                       \
  }                                                                           \
  __builtin_amdgcn_s_setprio(1);                                              \
  _Pragma("unroll") for (int i = 0; i < 4; ++i)                               \
  _Pragma("unroll") for (int j = 0; j < 4; ++j)                               \
    acc[i][j] = __builtin_amdgcn_mfma_f32_16x16x32_bf16(                      \
        af[i], bf[j], acc[i][j], 0, 0, 0);                                    \
  __builtin_amdgcn_s_setprio(0);

  // tile kt: stage kt+2 into buffer that died at kt-1; 1 vmcnt + 1 barrier
#define TILE(CB, SB, KT2)                                                     \
  do {                                                                        \
    STAGE(SB, KT2);                                                           \
    TILE_BODY(CB)                                                             \
    VMCNT(3);                   /* retires tile kt+1's 3 loads */             \
    BAR();                                                                    \
  } while (0)
#define TILE_LAST2(CB)                                                        \
  do {                                                                        \
    TILE_BODY(CB)                                                             \
    VMCNT(0);                   /* retires final tile's loads */              \
    BAR();                                                                    \
  } while (0)
#define TILE_FINAL(CB)                                                        \
  do {                                                                        \
    TILE_BODY(CB)                                                             \
  } while (0)

  // ---- prologue: stage tiles 0,1; retire tile 0 (leave tile 1 in flight)
  STAGE(0, 0);
  STAGE(1, 1);
  VMCNT(3);
  BAR();

  // ---- main: 42 iters x 3 tiles = tiles 0..125 (stages reach tile 127)
  for (int it = 0; it < 42; ++it) {
    const int k = 3 * it;
    TILE(0, 2, k + 2);
    TILE(1, 0, k + 3);
    TILE(2, 1, k + 4);
  }
  // ---- peel: tiles 126 (buf0), 127 (buf1)
  TILE_LAST2(0);
  TILE_FINAL(1);

  // epilogue: C col = lane&15, row = (lane>>4)*4 + r
  const int colb = n0 + wn * 64 + (lane & 15);
  const int rowb = m0 + wm * 64 + ((lane >> 4) << 2);
#pragma unroll
  for (int j = 0; j < 4; ++j) {
    const int col = colb + j * 16;
    const float bv = bias[col];
#pragma unroll
    for (int i = 0; i < 4; ++i) {
      const int row = rowb + i * 16;
#pragma unroll
      for (int r = 0; r < 4; ++r)
        out[(size_t)(row + r) * N_DIM + col] = acc[i][j][r] + bv;
    }
  }
#undef STAGE
#undef TILE_BODY
#undef TILE
#undef TILE_LAST2
#undef TILE_FINAL
}

// ================= fallback: 128x128 inline-dequant GEMM =================
#define FBM 128
#define FBN 128
#define FBK 64
#define FNT_N 86
#define FNT_M 64
#define FNB (FNT_N * FNT_M)

__global__ __launch_bounds__(256, 2) void gemm_fb_kernel(
    const float* __restrict__ Ain, const int* __restrict__ Wcodes,
    const float* __restrict__ scales, const float* __restrict__ bias,
    float* __restrict__ out) {
  __shared__ unsigned short lsA[FBM * FBK];
  __shared__ unsigned short lsB[FBN * FBK];

  const int t = threadIdx.x;
  const int bid = blockIdx.x;
  const int wg = (bid & 7) * (FNB / 8) + (bid >> 3);
  const int m0 = (wg / FNT_N) * FBM;
  const int n0 = (wg % FNT_N) * FBN;

  const int w = t >> 6;
  const int lane = t & 63;
  const int wm = w >> 1, wn = w & 1;
  const int srow = t >> 3;
  const int sp = t & 7;
  const int skc = sp ^ (srow & 7);

  f32x4 acc[4][4];
#pragma unroll
  for (int i = 0; i < 4; ++i)
#pragma unroll
    for (int j = 0; j < 4; ++j) {
      f32x4 z = {0.f, 0.f, 0.f, 0.f};
      acc[i][j] = z;
    }

  for (int kt = 0; kt < K_DIM / FBK; ++kt) {
    const int kg = kt * FBK + skc * 8;
#pragma unroll
    for (int c = 0; c < 4; ++c) {
      const int arow = m0 + c * 32 + srow;
      const float* ap = Ain + (size_t)arow * K_DIM + kg;
      float4 a0 = *(const float4*)ap;
      float4 a1 = *(const float4*)(ap + 4);
      uint4 va;
      va.x = pk2(a0.x, a0.y); va.y = pk2(a0.z, a0.w);
      va.z = pk2(a1.x, a1.y); va.w = pk2(a1.z, a1.w);
      *(uint4*)&lsA[(c * 32 + srow) * FBK + sp * 8] = va;

      const int nrow = n0 + c * 32 + srow;
      const float s = scales[nrow * NGROUPS + (kg >> 7)];
      const int4* wp = (const int4*)(Wcodes + (size_t)nrow * K_DIM + kg);
      int4 c0 = wp[0], c1 = wp[1];
      uint4 vb;
      vb.x = pk2((float)c0.x * s, (float)c0.y * s);
      vb.y = pk2((float)c0.z * s, (float)c0.w * s);
      vb.z = pk2((float)c1.x * s, (float)c1.y * s);
      vb.w = pk2((float)c1.z * s, (float)c1.w * s);
      *(uint4*)&lsB[(c * 32 + srow) * FBK + sp * 8] = vb;
    }
    __syncthreads();
#pragma unroll
    for (int kk = 0; kk < 2; ++kk) {
      bf16x8 af[4], bfr[4];
#pragma unroll
      for (int i = 0; i < 4; ++i) {
        const int row = wm * 64 + i * 16 + (lane & 15);
        const int pg = (kk * 4 + (lane >> 4)) ^ (row & 7);
        af[i] = *(const bf16x8*)&lsA[row * FBK + pg * 8];
      }
#pragma unroll
      for (int j = 0; j < 4; ++j) {
        const int row = wn * 64 + j * 16 + (lane & 15);
        const int pg = (kk * 4 + (lane >> 4)) ^ (row & 7);
        bfr[j] = *(const bf16x8*)&lsB[row * FBK + pg * 8];
      }
#pragma unroll
      for (int i = 0; i < 4; ++i)
#pragma unroll
        for (int j = 0; j < 4; ++j)
          acc[i][j] = __builtin_amdgcn_mfma_f32_16x16x32_bf16(af[i], bfr[j], acc[i][j], 0, 0, 0);
    }
    __syncthreads();
  }

  const int colb = n0 + wn * 64 + (lane & 15);
  const int rowb = m0 + wm * 64 + ((lane >> 4) << 2);
#pragma unroll
  for (int j = 0; j < 4; ++j) {
    const int col = colb + j * 16;
    const float bv = bias[col];
#pragma unroll
    for (int i = 0; i < 4; ++i) {
      const int row = rowb + i * 16;
#pragma unroll
      for (int r = 0; r < 4; ++r)
        out[(size_t)(row + r) * N_DIM + col] = acc[i][j][r] + bv;
    }
  }
}

extern "C" void kernel_launch(void* const* d_in, const int* in_sizes, int n_in,
                              void* d_out, int out_size, void* d_ws, size_t ws_size,
                              hipStream_t stream) {
  const float* Ain = (const float*)d_in[0];
  const int* Wc = (const int*)d_in[1];
  const float* sc = (const float*)d_in[2];
  const float* bias = (const float*)d_in[3];
  float* out = (float*)d_out;

  const size_t needA = (size_t)M_DIM * K_DIM * 2;
  const size_t needB = (size_t)N_DIM * K_DIM * 2;
  if (ws_size >= needA + needB) {
    unsigned short* wsA = (unsigned short*)d_ws;
    unsigned short* wsB = (unsigned short*)((char*)d_ws + needA);
    cvtA_kernel<<<(unsigned)((size_t)M_DIM * K_DIM / 8 / 256), 256, 0, stream>>>(Ain, wsA);
    dequantW_kernel<<<(unsigned)((size_t)N_DIM * K_DIM / 8 / 256), 256, 0, stream>>>(Wc, sc, wsB);
    gemm8_kernel<<<NB, 512, 0, stream>>>(wsA, wsB, bias, out);
  } else {
    gemm_fb_kernel<<<FNB, 256, 0, stream>>>(Ain, Wc, sc, bias, out);
  }
}

// Round 8
// 900.571 us; speedup vs baseline: 1.1839x; 1.1839x over previous
//
#include <hip/hip_runtime.h>
#include <hip/hip_bf16.h>
#include <cstdint>

#define M_DIM 8192
#define K_DIM 4096
#define N_DIM 11008
#define NGROUPS 32
#define KBLK 128          /* K / 32 k-tiles */

typedef __attribute__((ext_vector_type(4))) float f32x4;
typedef __attribute__((ext_vector_type(8))) __bf16 bf16x8;

__device__ __forceinline__ unsigned int f2bf(float f) {
  unsigned int u = __builtin_bit_cast(unsigned int, f);
  return (u + 0x7FFFu + ((u >> 16) & 1u)) >> 16;   // RNE f32->bf16
}
__device__ __forceinline__ unsigned int pk2(float lo, float hi) {
  return f2bf(lo) | (f2bf(hi) << 16);
}

// ---- prepass A: fp32 -> bf16, fragment-transposed layout ----
// granule g (16 B = 8 elems): r16 = g&15, kg = (g>>4)&3, kt = (g>>6)&127, rblk = g>>13
// holds A[rblk*16 + r16][kt*32 + kg*8 .. +8]  (lane l of a frag = granule l)
__global__ __launch_bounds__(256) void cvtA_t_kernel(const float* __restrict__ in,
                                                     unsigned short* __restrict__ outA) {
  unsigned g = blockIdx.x * 256 + threadIdx.x;
  unsigned r16 = g & 15, kg = (g >> 4) & 3, kt = (g >> 6) & 127, rblk = g >> 13;
  const float* p = in + (size_t)(rblk * 16 + r16) * K_DIM + kt * 32 + kg * 8;
  float4 a = *(const float4*)p, b = *(const float4*)(p + 4);
  uint4 v;
  v.x = pk2(a.x, a.y); v.y = pk2(a.z, a.w);
  v.z = pk2(b.x, b.y); v.w = pk2(b.z, b.w);
  *(uint4*)(outA + (size_t)g * 8) = v;
}

// ---- prepass W: int codes * scale -> bf16, fragment-transposed layout ----
__global__ __launch_bounds__(256) void dequantW_t_kernel(const int* __restrict__ wcodes,
                                                         const float* __restrict__ sc,
                                                         unsigned short* __restrict__ outB) {
  unsigned g = blockIdx.x * 256 + threadIdx.x;
  unsigned c16 = g & 15, kg = (g >> 4) & 3, kt = (g >> 6) & 127, cblk = g >> 13;
  unsigned col = cblk * 16 + c16;
  unsigned k0 = kt * 32 + kg * 8;
  float s = sc[col * NGROUPS + (k0 >> 7)];
  const int* p = wcodes + (size_t)col * K_DIM + k0;
  int4 c0 = *(const int4*)p, c1 = *(const int4*)(p + 4);
  uint4 v;
  v.x = pk2((float)c0.x * s, (float)c0.y * s);
  v.y = pk2((float)c0.z * s, (float)c0.w * s);
  v.z = pk2((float)c1.x * s, (float)c1.y * s);
  v.w = pk2((float)c1.z * s, (float)c1.w * s);
  *(uint4*)(outB + (size_t)g * 8) = v;
}

__device__ __forceinline__ void gload16(const void* g, void* l) {
  __builtin_amdgcn_global_load_lds((const __attribute__((address_space(1))) void*)g,
                                   (__attribute__((address_space(3))) void*)l,
                                   16, 0, 0);
}

// ====== 256x256, BK=32: A via LDS (transposed, conflict-free), B direct-to-reg ======
#define BM 256
#define BN 256
#define TILES_M (M_DIM / BM)      /* 32 */
#define TILES_N (N_DIM / BN)      /* 43 */
#define NB2 (TILES_M * TILES_N)   /* 1376, %8==0 */

#define VMCNT_(n) asm volatile("s_waitcnt vmcnt(" #n ")" ::: "memory")
#define VMCNT(n) VMCNT_(n)
#define FENCE() asm volatile("" ::: "memory")
#define BAR()                                   \
  do {                                          \
    asm volatile("" ::: "memory");              \
    __builtin_amdgcn_s_barrier();               \
    asm volatile("" ::: "memory");              \
  } while (0)

__global__ __launch_bounds__(512, 2) void gemm9_kernel(
    const unsigned short* __restrict__ A,   // transposed bf16 [M/16][KBLK][512]
    const unsigned short* __restrict__ B,   // transposed bf16 [N/16][KBLK][512]
    const float* __restrict__ bias,
    float* __restrict__ out) {
  __shared__ __align__(16) unsigned short sA[3][8192];   // 3 x 16 KiB

  const int t = threadIdx.x;
  const int bid = blockIdx.x;
  const int wg = (bid & 7) * (NB2 / 8) + (bid >> 3);   // bijective XCD swizzle
  const int m0 = (wg / TILES_N) * BM;
  const int n0 = (wg % TILES_N) * BN;

  const int w = t >> 6;
  const int lane = t & 63;
  const int wm = w >> 2;   // 0..1  -> rows wm*128..+128
  const int wn = w & 3;    // 0..3  -> cols wn*64..+64

  // A staging: wave w stages row-blocks (m0/16 + w) [call0] and (m0/16 + 8 + w) [call1].
  // Source granule = lane (layout == fragment order); LDS dest linear (uniform + lane*16B).
  const unsigned chunkbase = (unsigned)(m0 >> 4);
  const unsigned short* aS0 = A + (((size_t)(chunkbase + w)) << 16) + (unsigned)lane * 8;
  const unsigned short* aS1 = A + (((size_t)(chunkbase + 8 + w)) << 16) + (unsigned)lane * 8;
  const int ldd0 = w * 512;            // elems; + buf select
  const int ldd1 = 4096 + w * 512;

  // B fragment loads: frag j -> col-block (n0/16 + wn*4 + j), granule = lane.
  const unsigned short* bS = B + (((size_t)((n0 >> 4) + wn * 4)) << 16) + (unsigned)lane * 8;

  // A fragment LDS reads: frag i at rel row-block wm*8+i, granule = lane (contiguous,
  // stride 16 B/lane -> bank-conflict-free by construction).
  const int afb = (wm * 8) * 512 + lane * 8;

  f32x4 acc[8][4];
#pragma unroll
  for (int i = 0; i < 8; ++i)
#pragma unroll
    for (int j = 0; j < 4; ++j) {
      f32x4 z = {0.f, 0.f, 0.f, 0.f};
      acc[i][j] = z;
    }
  bf16x8 Ba[4], Bb[4];

#define LOADB(dst, kt)                                                        \
  _Pragma("unroll") for (int j = 0; j < 4; ++j)                               \
    dst[j] = *(const bf16x8*)(bS + (size_t)j * 65536 + (size_t)(kt) * 512);

#define STAGE(buf, kt)                                                        \
  do {                                                                        \
    gload16(aS0 + (unsigned)(kt) * 512, &sA[buf][ldd0]);                      \
    gload16(aS1 + (unsigned)(kt) * 512, &sA[buf][ldd1]);                      \
  } while (0)

  // TILE kt: ds_read A-frags(kt) | load B(kt+1)->BNXT | stage A(kt+2) | 32 MFMA |
  //          vmcnt(VN) | barrier.   FIFO: [Ast(kt+1)] + [B(kt+1)x4, Ast(kt+2)x2]
  //          -> VMCNT(2) retires Ast(kt+1)+B(kt+1), leaves Ast(kt+2).
#define TILE(CUR, NXT2, KT, BCUR, BNXT, DO_B, DO_ST, VN)                      \
  {                                                                           \
    bf16x8 af[8];                                                             \
    _Pragma("unroll") for (int i = 0; i < 8; ++i)                             \
      af[i] = *(const bf16x8*)&sA[CUR][afb + i * 512];                        \
    if (DO_B) { LOADB(BNXT, (KT) + 1); }                                      \
    FENCE();                                                                  \
    if (DO_ST) { STAGE(NXT2, (KT) + 2); }                                     \
    __builtin_amdgcn_s_setprio(1);                                            \
    _Pragma("unroll") for (int i = 0; i < 8; ++i)                             \
    _Pragma("unroll") for (int j = 0; j < 4; ++j)                             \
      acc[i][j] = __builtin_amdgcn_mfma_f32_16x16x32_bf16(af[i], BCUR[j],     \
                                                          acc[i][j], 0, 0, 0);\
    __builtin_amdgcn_s_setprio(0);                                            \
    VMCNT(VN);                                                                \
    BAR();                                                                    \
  }

  // ---- prologue: stage tiles 0,1; load B(0); full drain once
  STAGE(0, 0);
  STAGE(1, 1);
  LOADB(Ba, 0);
  VMCNT(0);
  BAR();

  // ---- main: 21 iters x 6 tiles = tiles 0..125 (lcm of 3-buf and 2-Bset)
  for (int it = 0; it < 21; ++it) {
    const int k6 = it * 6;
    TILE(0, 2, k6 + 0, Ba, Bb, 1, 1, 2)
    TILE(1, 0, k6 + 1, Bb, Ba, 1, 1, 2)
    TILE(2, 1, k6 + 2, Ba, Bb, 1, 1, 2)
    TILE(0, 2, k6 + 3, Bb, Ba, 1, 1, 2)
    TILE(1, 0, k6 + 4, Ba, Bb, 1, 1, 2)
    TILE(2, 1, k6 + 5, Bb, Ba, 1, 1, 2)
  }
  // ---- peel: kt=126 (buf0, cur Ba, load B(127), no stage, drain all),
  //            kt=127 (buf1, cur Bb, nothing outstanding)
  TILE(0, 2, 126, Ba, Bb, 1, 0, 0)
  TILE(1, 0, 127, Bb, Ba, 0, 0, 0)

  // ---- epilogue: C col = lane&15, row = (lane>>4)*4 + r
  const int colb = n0 + wn * 64 + (lane & 15);
  const int rowb = m0 + wm * 128 + ((lane >> 4) << 2);
#pragma unroll
  for (int j = 0; j < 4; ++j) {
    const int col = colb + j * 16;
    const float bv = bias[col];
#pragma unroll
    for (int ai = 0; ai < 8; ++ai) {
      const int row = rowb + ai * 16;
#pragma unroll
      for (int r = 0; r < 4; ++r)
        out[(size_t)(row + r) * N_DIM + col] = acc[ai][j][r] + bv;
    }
  }
#undef LOADB
#undef STAGE
#undef TILE
}

// ================= fallback: 128x128 inline-dequant GEMM =================
#define FBM 128
#define FBN 128
#define FBK 64
#define FNT_N 86
#define FNT_M 64
#define FNB (FNT_N * FNT_M)

__global__ __launch_bounds__(256, 2) void gemm_fb_kernel(
    const float* __restrict__ Ain, const int* __restrict__ Wcodes,
    const float* __restrict__ scales, const float* __restrict__ bias,
    float* __restrict__ out) {
  __shared__ unsigned short lsA[FBM * FBK];
  __shared__ unsigned short lsB[FBN * FBK];

  const int t = threadIdx.x;
  const int bid = blockIdx.x;
  const int wg = (bid & 7) * (FNB / 8) + (bid >> 3);
  const int m0 = (wg / FNT_N) * FBM;
  const int n0 = (wg % FNT_N) * FBN;

  const int w = t >> 6;
  const int lane = t & 63;
  const int wm = w >> 1, wn = w & 1;
  const int srow = t >> 3;
  const int sp = t & 7;
  const int skc = sp ^ (srow & 7);

  f32x4 acc[4][4];
#pragma unroll
  for (int i = 0; i < 4; ++i)
#pragma unroll
    for (int j = 0; j < 4; ++j) {
      f32x4 z = {0.f, 0.f, 0.f, 0.f};
      acc[i][j] = z;
    }

  for (int kt = 0; kt < K_DIM / FBK; ++kt) {
    const int kg = kt * FBK + skc * 8;
#pragma unroll
    for (int c = 0; c < 4; ++c) {
      const int arow = m0 + c * 32 + srow;
      const float* ap = Ain + (size_t)arow * K_DIM + kg;
      float4 a0 = *(const float4*)ap;
      float4 a1 = *(const float4*)(ap + 4);
      uint4 va;
      va.x = pk2(a0.x, a0.y); va.y = pk2(a0.z, a0.w);
      va.z = pk2(a1.x, a1.y); va.w = pk2(a1.z, a1.w);
      *(uint4*)&lsA[(c * 32 + srow) * FBK + sp * 8] = va;

      const int nrow = n0 + c * 32 + srow;
      const float s = scales[nrow * NGROUPS + (kg >> 7)];
      const int4* wp = (const int4*)(Wcodes + (size_t)nrow * K_DIM + kg);
      int4 c0 = wp[0], c1 = wp[1];
      uint4 vb;
      vb.x = pk2((float)c0.x * s, (float)c0.y * s);
      vb.y = pk2((float)c0.z * s, (float)c0.w * s);
      vb.z = pk2((float)c1.x * s, (float)c1.y * s);
      vb.w = pk2((float)c1.z * s, (float)c1.w * s);
      *(uint4*)&lsB[(c * 32 + srow) * FBK + sp * 8] = vb;
    }
    __syncthreads();
#pragma unroll
    for (int kk = 0; kk < 2; ++kk) {
      bf16x8 af[4], bfr[4];
#pragma unroll
      for (int i = 0; i < 4; ++i) {
        const int row = wm * 64 + i * 16 + (lane & 15);
        const int pg = (kk * 4 + (lane >> 4)) ^ (row & 7);
        af[i] = *(const bf16x8*)&lsA[row * FBK + pg * 8];
      }
#pragma unroll
      for (int j = 0; j < 4; ++j) {
        const int row = wn * 64 + j * 16 + (lane & 15);
        const int pg = (kk * 4 + (lane >> 4)) ^ (row & 7);
        bfr[j] = *(const bf16x8*)&lsB[row * FBK + pg * 8];
      }
#pragma unroll
      for (int i = 0; i < 4; ++i)
#pragma unroll
        for (int j = 0; j < 4; ++j)
          acc[i][j] = __builtin_amdgcn_mfma_f32_16x16x32_bf16(af[i], bfr[j], acc[i][j], 0, 0, 0);
    }
    __syncthreads();
  }

  const int colb = n0 + wn * 64 + (lane & 15);
  const int rowb = m0 + wm * 64 + ((lane >> 4) << 2);
#pragma unroll
  for (int j = 0; j < 4; ++j) {
    const int col = colb + j * 16;
    const float bv = bias[col];
#pragma unroll
    for (int i = 0; i < 4; ++i) {
      const int row = rowb + i * 16;
#pragma unroll
      for (int r = 0; r < 4; ++r)
        out[(size_t)(row + r) * N_DIM + col] = acc[i][j][r] + bv;
    }
  }
}

extern "C" void kernel_launch(void* const* d_in, const int* in_sizes, int n_in,
                              void* d_out, int out_size, void* d_ws, size_t ws_size,
                              hipStream_t stream) {
  const float* Ain = (const float*)d_in[0];
  const int* Wc = (const int*)d_in[1];
  const float* sc = (const float*)d_in[2];
  const float* bias = (const float*)d_in[3];
  float* out = (float*)d_out;

  const size_t needA = (size_t)M_DIM * K_DIM * 2;
  const size_t needB = (size_t)N_DIM * K_DIM * 2;
  if (ws_size >= needA + needB) {
    unsigned short* wsA = (unsigned short*)d_ws;
    unsigned short* wsB = (unsigned short*)((char*)d_ws + needA);
    cvtA_t_kernel<<<(unsigned)((size_t)M_DIM * K_DIM / 8 / 256), 256, 0, stream>>>(Ain, wsA);
    dequantW_t_kernel<<<(unsigned)((size_t)N_DIM * K_DIM / 8 / 256), 256, 0, stream>>>(Wc, sc, wsB);
    gemm9_kernel<<<NB2, 512, 0, stream>>>(wsA, wsB, bias, out);
  } else {
    gemm_fb_kernel<<<FNB, 256, 0, stream>>>(Ain, Wc, sc, bias, out);
  }
}